// Round 7
// baseline (648.516 us; speedup 1.0000x reference)
//
#include <hip/hip_runtime.h>

#define IN_F 8192
#define OUT_F 8192
#define THRESHOLD_F 50.0f
#define TARGET_RATE 0.1f

// clang-native vector type: required by __builtin_nontemporal_load/store
typedef float f32x4 __attribute__((ext_vector_type(4)));

// Round-7: DENSE-BAND persistent waves.
//
// Theory: rounds 0-6 all launched 8192 resident waves (= full chip wave
// capacity), each streaming its own 32 KB row of S, E and T simultaneously
// -> ~24K concurrent DRAM streams > HBM bank count -> row-buffer thrash,
// ~5.0 TB/s vs the 6.3-6.6 TB/s dense-front fill/copy ceiling. This round
// keeps the measured-best round-6 per-row body (front-loaded E register
// batches, all-nt, branch-free epilogue) but launches only 512 persistent
// blocks (2048 waves); wave w processes rows w, w+2048, w+4096, w+6144.
// At any instant the active set is a dense ~2048-consecutive-row band per
// array: 4x fewer concurrent streams, consecutive waves on consecutive rows.
// 2048 waves x ~8-16KB in flight >> the ~6 MB BW*latency product, so
// latency hiding is preserved (fills saturate BW at 10% occupancy).
__global__ __launch_bounds__(256) void snn_wave_fused(
    const float* __restrict__ spike_input,        // [IN_F]
    const float* __restrict__ synapse_states,     // [OUT_F, IN_F]
    const float* __restrict__ membrane_potential, // [OUT_F]
    const float* __restrict__ adaptive_threshold, // [OUT_F]
    const float* __restrict__ eligibility_trace,  // [OUT_F, IN_F]
    float* __restrict__ out_spikes,               // [OUT_F]
    float* __restrict__ out_vmem,                 // [OUT_F]
    float* __restrict__ out_thresh,               // [OUT_F]
    float* __restrict__ out_trace)                // [OUT_F, IN_F]
{
    const int wid  = (blockIdx.x << 2) + (threadIdx.x >> 6);  // 0..2047
    const int lane = threadIdx.x & 63;

    const f32x4* x4 = (const f32x4*)spike_input;

    #pragma unroll 1   // keep the 4-row loop rolled: compact I-cache, dense band
    for (int p = 0; p < 4; ++p) {
        const int row = wid + (p << 11);          // dense 2048-row band per phase

        const f32x4* s4 = (const f32x4*)(synapse_states + (size_t)row * IN_F);
        const f32x4* e4 = (const f32x4*)(eligibility_trace + (size_t)row * IN_F);
        f32x4*       t4 = (f32x4*)(out_trace + (size_t)row * IN_F);

        // ---- Phase 1: current = sum_i (S[row,i] > 50) * clip(2*x[i],0,1) ----
        float sum = 0.0f;
        #pragma unroll 8
        for (int k = 0; k < 32; ++k) {
            int idx = lane + (k << 6);             // f32x4 idx in [0, 2048)
            f32x4 s = __builtin_nontemporal_load(&s4[idx]);  // single-use stream
            f32x4 v = x4[idx];                               // hot in cache
            v.x = fminf(fmaxf(v.x * 2.0f, 0.0f), 1.0f);
            v.y = fminf(fmaxf(v.y * 2.0f, 0.0f), 1.0f);
            v.z = fminf(fmaxf(v.z * 2.0f, 0.0f), 1.0f);
            v.w = fminf(fmaxf(v.w * 2.0f, 0.0f), 1.0f);
            sum += (s.x > THRESHOLD_F ? v.x : 0.0f)
                 + (s.y > THRESHOLD_F ? v.y : 0.0f)
                 + (s.z > THRESHOLD_F ? v.z : 0.0f)
                 + (s.w > THRESHOLD_F ? v.w : 0.0f);
        }

        // ---- Phase 1.5: issue E batch 0 (16 x f32x4) before the butterfly.
        // No dependency on sum/spike -> rides out the reduce + neuron update.
        f32x4 e0[16];
        #pragma unroll
        for (int k = 0; k < 16; ++k)
            e0[k] = __builtin_nontemporal_load(&e4[lane + (k << 6)]);

        // Butterfly reduction: every lane ends with the identical full sum.
        // Needs only S; E batch 0 stays in flight across it.
        #pragma unroll
        for (int m = 1; m < 64; m <<= 1)
            sum += __shfl_xor(sum, m, 64);

        // ---- Phase 2: neuron update (all lanes compute; lane 0 writes) ----
        float v_mem = membrane_potential[row] * 0.7f + sum;  // wave-broadcast
        float thr   = adaptive_threshold[row];
        float spike = (v_mem >= thr) ? 1.0f : 0.0f;
        if (lane == 0) {
            out_spikes[row] = spike;
            out_vmem[row]   = v_mem * (1.0f - spike) * 0.3f;
            out_thresh[row] = fminf(fmaxf(thr + (spike - TARGET_RATE) * 0.05f, 0.5f), 5.0f);
        }

        // ---- Phase 2.5: issue E batch 1 BEFORE any store of batch 0 ----
        f32x4 e1[16];
        #pragma unroll
        for (int k = 0; k < 16; ++k)
            e1[k] = __builtin_nontemporal_load(&e4[lane + ((k + 16) << 6)]);

        // ---- Phase 3: write tail; reads never wait behind stores ----
        #pragma unroll
        for (int k = 0; k < 16; ++k) {
            int idx = lane + (k << 6);
            f32x4 v = x4[idx];                    // cache-hot
            f32x4 t;
            t.x = fminf(fmaxf(e0[k].x * 0.8f + spike * fminf(fmaxf(v.x * 2.0f, 0.0f), 1.0f), 0.0f), 3.0f);
            t.y = fminf(fmaxf(e0[k].y * 0.8f + spike * fminf(fmaxf(v.y * 2.0f, 0.0f), 1.0f), 0.0f), 3.0f);
            t.z = fminf(fmaxf(e0[k].z * 0.8f + spike * fminf(fmaxf(v.z * 2.0f, 0.0f), 1.0f), 0.0f), 3.0f);
            t.w = fminf(fmaxf(e0[k].w * 0.8f + spike * fminf(fmaxf(v.w * 2.0f, 0.0f), 1.0f), 0.0f), 3.0f);
            __builtin_nontemporal_store(t, &t4[idx]);
        }
        #pragma unroll
        for (int k = 0; k < 16; ++k) {
            int idx = lane + ((k + 16) << 6);
            f32x4 v = x4[idx];
            f32x4 t;
            t.x = fminf(fmaxf(e1[k].x * 0.8f + spike * fminf(fmaxf(v.x * 2.0f, 0.0f), 1.0f), 0.0f), 3.0f);
            t.y = fminf(fmaxf(e1[k].y * 0.8f + spike * fminf(fmaxf(v.y * 2.0f, 0.0f), 1.0f), 0.0f), 3.0f);
            t.z = fminf(fmaxf(e1[k].z * 0.8f + spike * fminf(fmaxf(v.z * 2.0f, 0.0f), 1.0f), 0.0f), 3.0f);
            t.w = fminf(fmaxf(e1[k].w * 0.8f + spike * fminf(fmaxf(v.w * 2.0f, 0.0f), 1.0f), 0.0f), 3.0f);
            __builtin_nontemporal_store(t, &t4[idx]);
        }
    }
}

extern "C" void kernel_launch(void* const* d_in, const int* in_sizes, int n_in,
                              void* d_out, int out_size, void* d_ws, size_t ws_size,
                              hipStream_t stream) {
    const float* spike_input        = (const float*)d_in[0];
    const float* synapse_states     = (const float*)d_in[1];
    const float* membrane_potential = (const float*)d_in[2];
    const float* adaptive_threshold = (const float*)d_in[3];
    const float* eligibility_trace  = (const float*)d_in[4];

    float* out = (float*)d_out;
    float* out_spikes = out;                      // [OUT_F]
    float* out_vmem   = out + OUT_F;              // [OUT_F]
    float* out_thresh = out + 2 * OUT_F;          // [OUT_F]
    float* out_trace  = out + 3 * OUT_F;          // [OUT_F, IN_F]

    // 512 persistent blocks (2048 waves); each wave strides 4 dense row-bands.
    snn_wave_fused<<<512, 256, 0, stream>>>(
        spike_input, synapse_states, membrane_potential, adaptive_threshold,
        eligibility_trace, out_spikes, out_vmem, out_thresh, out_trace);
}